// Round 1
// baseline (2082.272 us; speedup 1.0000x reference)
//
#include <hip/hip_runtime.h>
#include <math.h>

// Swin block, fp32 correctness-first baseline.
// B=64, H=W=56, C=96, WS=7, SS=3, NH=3, HD=32, N=49, nW=64 (8x8 windows).

#define TOK 49
#define CDIM 96
#define SCALE_QK 0.17677669529663687f  // 32^-0.5

// ---------------- Kernel 1: LN1 + shift + window attention + proj + residual ----------------
__global__ __launch_bounds__(512) void swin_attn_kernel(
    const float* __restrict__ x,
    const float* __restrict__ attn_mask,
    const float* __restrict__ ln1_g, const float* __restrict__ ln1_b,
    const float* __restrict__ qkv_w, const float* __restrict__ qkv_b,
    const float* __restrict__ rel_bias_table, const int* __restrict__ rel_index,
    const float* __restrict__ proj_w, const float* __restrict__ proj_b,
    float* __restrict__ h_out)
{
    __shared__ float xt[49][100];    // LN'd window tokens; reused as attn output (49x96)
    __shared__ float qkvs[49][292];  // per-token q|k|v (cols 0..95 q, 96..191 k, 192..287 v)
    __shared__ float sc[49][49];     // scores for current head

    const int w    = blockIdx.x;
    const int b    = w >> 6;        // batch
    const int widx = w & 63;        // window within image
    const int wi   = widx >> 3, wj = widx & 7;
    const int tid  = threadIdx.x;
    const int wave = tid >> 6, lane = tid & 63;

    // ---- Phase 1: LayerNorm1 + shifted-window gather (roll -3,-3) ----
    for (int n = wave; n < TOK; n += 8) {
        const int p = n / 7, q = n - 7 * p;
        int sr = wi * 7 + p + 3; if (sr >= 56) sr -= 56;
        int scol = wj * 7 + q + 3; if (scol >= 56) scol -= 56;
        const float* xr = x + ((size_t)b * 3136 + (size_t)(sr * 56 + scol)) * CDIM;
        float v0 = xr[lane];
        float v1 = (lane < 32) ? xr[64 + lane] : 0.f;
        float s = v0 + v1, ss = v0 * v0 + v1 * v1;
        #pragma unroll
        for (int m = 1; m < 64; m <<= 1) { s += __shfl_xor(s, m); ss += __shfl_xor(ss, m); }
        const float mean = s * (1.f / 96.f);
        const float var  = ss * (1.f / 96.f) - mean * mean;
        const float rstd = rsqrtf(var + 1e-5f);
        xt[n][lane] = (v0 - mean) * rstd * ln1_g[lane] + ln1_b[lane];
        if (lane < 32)
            xt[n][64 + lane] = (v1 - mean) * rstd * ln1_g[64 + lane] + ln1_b[64 + lane];
    }
    __syncthreads();

    // ---- Phase 2: qkv = xt @ qkv_w^T + qkv_b  (49x96 @ 96x288) ----
    // tasks: 7 row-groups (7 rows each) x 72 col-groups (4 cols each) = 504
    for (int t = tid; t < 504; t += 512) {
        const int rg = t / 72, cg = t - 72 * rg;
        float acc[7][4];
        #pragma unroll
        for (int r = 0; r < 7; ++r)
            #pragma unroll
            for (int j = 0; j < 4; ++j) acc[r][j] = 0.f;
        const float* wb = qkv_w + (size_t)(cg * 4) * 96;
        for (int k4 = 0; k4 < 24; ++k4) {
            float4 wv[4];
            #pragma unroll
            for (int j = 0; j < 4; ++j)
                wv[j] = *(const float4*)(wb + j * 96 + k4 * 4);
            #pragma unroll
            for (int r = 0; r < 7; ++r) {
                const float4 xv = *(const float4*)(&xt[rg * 7 + r][k4 * 4]);
                #pragma unroll
                for (int j = 0; j < 4; ++j)
                    acc[r][j] = fmaf(xv.x, wv[j].x, fmaf(xv.y, wv[j].y,
                                fmaf(xv.z, wv[j].z, fmaf(xv.w, wv[j].w, acc[r][j]))));
            }
        }
        #pragma unroll
        for (int r = 0; r < 7; ++r)
            #pragma unroll
            for (int j = 0; j < 4; ++j)
                qkvs[rg * 7 + r][cg * 4 + j] = acc[r][j] + qkv_b[cg * 4 + j];
    }
    __syncthreads();

    // ---- Phase 3: per-head attention ----
    const float* maskrow = attn_mask + (size_t)widx * 2401;
    for (int h = 0; h < 3; ++h) {
        // scores S = (q*scale) k^T + rel_bias + mask
        for (int idx = tid; idx < 2401; idx += 512) {
            const int i = idx / 49, j = idx - 49 * i;
            const float* qp = &qkvs[i][h * 32];
            const float* kp = &qkvs[j][96 + h * 32];
            float acc = 0.f;
            #pragma unroll
            for (int k4 = 0; k4 < 8; ++k4) {
                const float4 a  = *(const float4*)(qp + k4 * 4);
                const float4 bb = *(const float4*)(kp + k4 * 4);
                acc = fmaf(a.x, bb.x, fmaf(a.y, bb.y, fmaf(a.z, bb.z, fmaf(a.w, bb.w, acc))));
            }
            const float bias = rel_bias_table[rel_index[idx] * 3 + h];
            sc[i][j] = acc * SCALE_QK + bias + maskrow[idx];
        }
        __syncthreads();
        // softmax per row (one wave per row)
        for (int row = wave; row < TOK; row += 8) {
            float v = (lane < 49) ? sc[row][lane] : -3.0e38f;
            float mx = v;
            #pragma unroll
            for (int m = 1; m < 64; m <<= 1) mx = fmaxf(mx, __shfl_xor(mx, m));
            float e = (lane < 49) ? __expf(v - mx) : 0.f;
            float ssum = e;
            #pragma unroll
            for (int m = 1; m < 64; m <<= 1) ssum += __shfl_xor(ssum, m);
            if (lane < 49) sc[row][lane] = e / ssum;
        }
        __syncthreads();
        // PV: out[i][d] = sum_m P[i][m] * v[m][d]   (49x49 @ 49x32), float4 over d
        for (int idx = tid; idx < 392; idx += 512) {
            const int i = idx >> 3, d4 = (idx & 7) * 4;
            float4 acc = make_float4(0.f, 0.f, 0.f, 0.f);
            for (int m = 0; m < 49; ++m) {
                const float pm = sc[i][m];
                const float4 vv = *(const float4*)(&qkvs[m][192 + h * 32 + d4]);
                acc.x = fmaf(pm, vv.x, acc.x);
                acc.y = fmaf(pm, vv.y, acc.y);
                acc.z = fmaf(pm, vv.z, acc.z);
                acc.w = fmaf(pm, vv.w, acc.w);
            }
            *(float4*)(&xt[i][h * 32 + d4]) = acc;
        }
        __syncthreads();
    }

    // ---- Phase 4: proj + residual + window-reverse/unshift scatter ----
    // tasks: 7 row-groups x 24 col-groups(4) = 168 (threads 168..511 idle)
    for (int t = tid; t < 168; t += 512) {
        const int rg = t / 24, cg = t - 24 * rg;
        float acc[7][4];
        #pragma unroll
        for (int r = 0; r < 7; ++r)
            #pragma unroll
            for (int j = 0; j < 4; ++j) acc[r][j] = 0.f;
        const float* wb = proj_w + (size_t)(cg * 4) * 96;
        for (int k4 = 0; k4 < 24; ++k4) {
            float4 wv[4];
            #pragma unroll
            for (int j = 0; j < 4; ++j)
                wv[j] = *(const float4*)(wb + j * 96 + k4 * 4);
            #pragma unroll
            for (int r = 0; r < 7; ++r) {
                const float4 av = *(const float4*)(&xt[rg * 7 + r][k4 * 4]);
                #pragma unroll
                for (int j = 0; j < 4; ++j)
                    acc[r][j] = fmaf(av.x, wv[j].x, fmaf(av.y, wv[j].y,
                                fmaf(av.z, wv[j].z, fmaf(av.w, wv[j].w, acc[r][j]))));
            }
        }
        // token n = rg*7 + r  ->  p = rg, q = r
        #pragma unroll
        for (int r = 0; r < 7; ++r) {
            int sr = wi * 7 + rg + 3; if (sr >= 56) sr -= 56;
            int scol = wj * 7 + r + 3; if (scol >= 56) scol -= 56;
            const size_t base = ((size_t)b * 3136 + (size_t)(sr * 56 + scol)) * CDIM + cg * 4;
            #pragma unroll
            for (int j = 0; j < 4; ++j)
                h_out[base + j] = acc[r][j] + proj_b[cg * 4 + j] + x[base + j];
        }
    }
}

// ---------------- Kernel 2: LN2 + fc1 + GELU + fc2 + residual (in-place on h) ----------------
__global__ __launch_bounds__(512) void swin_mlp_kernel(
    const float* __restrict__ ln2_g, const float* __restrict__ ln2_b,
    const float* __restrict__ fc1_w, const float* __restrict__ fc1_b,
    const float* __restrict__ fc2_w, const float* __restrict__ fc2_b,
    float* io)  // holds h on entry (rows owned exclusively by this block), final out on exit
{
    __shared__ float xs[64][100];   // LN2'd rows
    __shared__ float m1[64][388];   // fc1 output after GELU

    const int tid  = threadIdx.x;
    const int wave = tid >> 6, lane = tid & 63;
    const size_t r0 = (size_t)blockIdx.x * 64;

    // ---- LN2 ----
    for (int n = wave; n < 64; n += 8) {
        const float* xr = io + (r0 + n) * CDIM;
        float v0 = xr[lane];
        float v1 = (lane < 32) ? xr[64 + lane] : 0.f;
        float s = v0 + v1, ss = v0 * v0 + v1 * v1;
        #pragma unroll
        for (int m = 1; m < 64; m <<= 1) { s += __shfl_xor(s, m); ss += __shfl_xor(ss, m); }
        const float mean = s * (1.f / 96.f);
        const float var  = ss * (1.f / 96.f) - mean * mean;
        const float rstd = rsqrtf(var + 1e-5f);
        xs[n][lane] = (v0 - mean) * rstd * ln2_g[lane] + ln2_b[lane];
        if (lane < 32)
            xs[n][64 + lane] = (v1 - mean) * rstd * ln2_g[64 + lane] + ln2_b[64 + lane];
    }
    __syncthreads();

    // ---- fc1 + exact GELU: 64x96 @ 96x384 ----
    // tasks: 8 row-groups (8 rows) x 96 col-groups (4 cols) = 768
    for (int t = tid; t < 768; t += 512) {
        const int rg = t / 96, cg = t - 96 * rg;
        float acc[8][4];
        #pragma unroll
        for (int r = 0; r < 8; ++r)
            #pragma unroll
            for (int j = 0; j < 4; ++j) acc[r][j] = 0.f;
        const float* wb = fc1_w + (size_t)(cg * 4) * 96;
        for (int k4 = 0; k4 < 24; ++k4) {
            float4 wv[4];
            #pragma unroll
            for (int j = 0; j < 4; ++j)
                wv[j] = *(const float4*)(wb + j * 96 + k4 * 4);
            #pragma unroll
            for (int r = 0; r < 8; ++r) {
                const float4 xv = *(const float4*)(&xs[rg * 8 + r][k4 * 4]);
                #pragma unroll
                for (int j = 0; j < 4; ++j)
                    acc[r][j] = fmaf(xv.x, wv[j].x, fmaf(xv.y, wv[j].y,
                                fmaf(xv.z, wv[j].z, fmaf(xv.w, wv[j].w, acc[r][j]))));
            }
        }
        #pragma unroll
        for (int r = 0; r < 8; ++r)
            #pragma unroll
            for (int j = 0; j < 4; ++j) {
                const float u = acc[r][j] + fc1_b[cg * 4 + j];
                m1[rg * 8 + r][cg * 4 + j] = 0.5f * u * (1.f + erff(u * 0.70710678118654752f));
            }
    }
    __syncthreads();

    // ---- fc2 + residual: 64x384 @ 384x96, out = h + fc2(m1) ----
    // tasks: 8 row-groups (8 rows) x 48 col-groups (2 cols) = 384
    for (int t = tid; t < 384; t += 512) {
        const int rg = t / 48, cg = t - 48 * rg;
        float acc[8][2];
        #pragma unroll
        for (int r = 0; r < 8; ++r) { acc[r][0] = 0.f; acc[r][1] = 0.f; }
        const float* wb = fc2_w + (size_t)(cg * 2) * 384;
        for (int k4 = 0; k4 < 96; ++k4) {
            float4 wv[2];
            #pragma unroll
            for (int j = 0; j < 2; ++j)
                wv[j] = *(const float4*)(wb + j * 384 + k4 * 4);
            #pragma unroll
            for (int r = 0; r < 8; ++r) {
                const float4 mv = *(const float4*)(&m1[rg * 8 + r][k4 * 4]);
                #pragma unroll
                for (int j = 0; j < 2; ++j)
                    acc[r][j] = fmaf(mv.x, wv[j].x, fmaf(mv.y, wv[j].y,
                                fmaf(mv.z, wv[j].z, fmaf(mv.w, wv[j].w, acc[r][j]))));
            }
        }
        #pragma unroll
        for (int r = 0; r < 8; ++r)
            #pragma unroll
            for (int j = 0; j < 2; ++j) {
                const size_t o = (r0 + rg * 8 + r) * CDIM + cg * 2 + j;
                io[o] = io[o] + acc[r][j] + fc2_b[cg * 2 + j];
            }
    }
}

extern "C" void kernel_launch(void* const* d_in, const int* in_sizes, int n_in,
                              void* d_out, int out_size, void* d_ws, size_t ws_size,
                              hipStream_t stream) {
    (void)n_in; (void)out_size; (void)d_ws; (void)ws_size;
    const float* x        = (const float*)d_in[0];
    const float* attn_msk = (const float*)d_in[1];
    const float* ln1_g    = (const float*)d_in[2];
    const float* ln1_b    = (const float*)d_in[3];
    const float* qkv_w    = (const float*)d_in[4];
    const float* qkv_b    = (const float*)d_in[5];
    const float* rel_tab  = (const float*)d_in[6];
    const int*   rel_idx  = (const int*)d_in[7];
    const float* proj_w   = (const float*)d_in[8];
    const float* proj_b   = (const float*)d_in[9];
    const float* ln2_g    = (const float*)d_in[10];
    const float* ln2_b    = (const float*)d_in[11];
    const float* fc1_w    = (const float*)d_in[12];
    const float* fc1_b    = (const float*)d_in[13];
    const float* fc2_w    = (const float*)d_in[14];
    const float* fc2_b    = (const float*)d_in[15];
    float* out = (float*)d_out;

    const int B = in_sizes[0] / (3136 * 96);   // 64

    // Kernel 1 writes h = x + attn(...) into d_out (full overwrite).
    swin_attn_kernel<<<B * 64, 512, 0, stream>>>(
        x, attn_msk, ln1_g, ln1_b, qkv_w, qkv_b, rel_tab, rel_idx, proj_w, proj_b, out);

    // Kernel 2 computes out = h + MLP(LN2(h)) in-place (rows block-exclusive).
    swin_mlp_kernel<<<(B * 3136) / 64, 512, 0, stream>>>(
        ln2_g, ln2_b, fc1_w, fc1_b, fc2_w, fc2_b, out);
}

// Round 2
// 711.270 us; speedup vs baseline: 2.9275x; 2.9275x over previous
//
#include <hip/hip_runtime.h>
#include <math.h>

// Swin block, bf16-MFMA version.
// B=64, H=W=56, C=96, WS=7, SS=3, NH=3, HD=32, N=49 (padded to 64), nW=64.

#define CDIM 96
#define SCALE_QK 0.17677669529663687f  // 32^-0.5

typedef __attribute__((ext_vector_type(8))) short bf16x8;
typedef __attribute__((ext_vector_type(4))) float f32x4;

__device__ inline unsigned short f2b(float f) {
    union { float f; unsigned u; } v; v.f = f;
    unsigned r = v.u + 0x7FFF + ((v.u >> 16) & 1);   // round-to-nearest-even
    return (unsigned short)(r >> 16);
}

// ---------------- Kernel 0: convert weights fp32 -> bf16 into ws ----------------
// layout in ws (elements): qkv_w [288*96] @0, proj_w [96*96] @27648,
//                          fc1_w [384*96] @36864, fc2_w [96*384] @73728
__global__ __launch_bounds__(256) void conv_w_kernel(
    const float* __restrict__ qkv_w, const float* __restrict__ proj_w,
    const float* __restrict__ fc1_w, const float* __restrict__ fc2_w,
    unsigned short* __restrict__ ws)
{
    const int i = blockIdx.x * 256 + threadIdx.x;
    if (i < 27648)       ws[i] = f2b(qkv_w[i]);
    else if (i < 36864)  ws[i] = f2b(proj_w[i - 27648]);
    else if (i < 73728)  ws[i] = f2b(fc1_w[i - 36864]);
    else if (i < 110592) ws[i] = f2b(fc2_w[i - 73728]);
}

// ---------------- Kernel 1: LN1 + shift + window attention (MFMA) + proj + residual ----------------
__global__ __launch_bounds__(256) void swin_attn_mfma(
    const float* __restrict__ x,
    const float* __restrict__ attn_mask,
    const float* __restrict__ ln1_g, const float* __restrict__ ln1_b,
    const float* __restrict__ qkv_b,
    const float* __restrict__ rel_bias_table, const int* __restrict__ rel_index,
    const float* __restrict__ proj_b,
    const unsigned short* __restrict__ wqkv,   // [288][96] bf16
    const unsigned short* __restrict__ wproj,  // [96][96] bf16
    float* __restrict__ h_out)
{
    __shared__ unsigned short xt[64][104];   // LN'd tokens; reused as attn-out bf16
    __shared__ unsigned short qs[64][104];   // q (pre-scaled, +bias), row-major
    __shared__ unsigned short kss[64][104];  // k (+bias), row-major
    __shared__ unsigned short vs[96][72];    // v (+bias), TRANSPOSED [feature][token]
    __shared__ float          sc[64][66];    // raw scores per head
    __shared__ unsigned short ps[64][72];    // softmax probs bf16

    const int w = blockIdx.x, b = w >> 6, widx = w & 63;
    const int wi = widx >> 3, wj = widx & 7;
    const int tid = threadIdx.x, wave = tid >> 6, lane = tid & 63;
    const int l15 = lane & 15, lk = (lane >> 4) * 8, lr = (lane >> 4) * 4;

    // ---- Phase 1: LN1 + shifted-window gather (roll -3,-3), pad rows 49..63 with 0 ----
    for (int n = wave; n < 64; n += 4) {
        if (n < 49) {
            const int p = n / 7, q = n - 7 * p;
            int sr = wi * 7 + p + 3;  if (sr >= 56) sr -= 56;
            int scl = wj * 7 + q + 3; if (scl >= 56) scl -= 56;
            const float* xr = x + ((size_t)b * 3136 + (size_t)(sr * 56 + scl)) * CDIM;
            float v0 = xr[lane];
            float v1 = (lane < 32) ? xr[64 + lane] : 0.f;
            float s = v0 + v1, ss2 = v0 * v0 + v1 * v1;
            #pragma unroll
            for (int m = 1; m < 64; m <<= 1) { s += __shfl_xor(s, m); ss2 += __shfl_xor(ss2, m); }
            const float mean = s * (1.f / 96.f);
            const float var  = ss2 * (1.f / 96.f) - mean * mean;
            const float rstd = rsqrtf(var + 1e-5f);
            xt[n][lane] = f2b((v0 - mean) * rstd * ln1_g[lane] + ln1_b[lane]);
            if (lane < 32)
                xt[n][64 + lane] = f2b((v1 - mean) * rstd * ln1_g[64 + lane] + ln1_b[64 + lane]);
        } else {
            xt[n][lane] = 0;
            if (lane < 32) xt[n][64 + lane] = 0;
        }
    }
    __syncthreads();

    // ---- Phase 2: qkv = xt @ Wqkv^T + b  (64x96 @ 96x288), 4 Mt x 18 Nt tiles ----
    for (int t = wave; t < 72; t += 4) {
        const int mt = t / 18, nt = t - 18 * mt;
        f32x4 acc = {0.f, 0.f, 0.f, 0.f};
        #pragma unroll
        for (int ksp = 0; ksp < 3; ++ksp) {
            bf16x8 a  = *(const bf16x8*)&xt[mt * 16 + l15][ksp * 32 + lk];
            bf16x8 bb = *(const bf16x8*)(wqkv + (size_t)(nt * 16 + l15) * 96 + ksp * 32 + lk);
            acc = __builtin_amdgcn_mfma_f32_16x16x32_bf16(a, bb, acc, 0, 0, 0);
        }
        const int colf = nt * 16 + l15;
        const float bias = qkv_b[colf];
        #pragma unroll
        for (int r = 0; r < 4; ++r) {
            const int rowt = mt * 16 + lr + r;
            const float vv = acc[r] + bias;
            if (colf < 96)       qs[rowt][colf] = f2b(vv * SCALE_QK);
            else if (colf < 192) kss[rowt][colf - 96] = f2b(vv);
            else                 vs[colf - 192][rowt] = f2b(vv);
        }
    }
    __syncthreads();

    // ---- Phase 3: per-head attention ----
    const float* maskrow = attn_mask + (size_t)widx * 2401;
    for (int h = 0; h < 3; ++h) {
        // scores = q k^T  (64x32 @ 32x64), 4x4 tiles, K=32 (one MFMA each)
        for (int t = wave; t < 16; t += 4) {
            const int mt = t >> 2, nt = t & 3;
            f32x4 acc = {0.f, 0.f, 0.f, 0.f};
            bf16x8 a  = *(const bf16x8*)&qs[mt * 16 + l15][h * 32 + lk];
            bf16x8 bb = *(const bf16x8*)&kss[nt * 16 + l15][h * 32 + lk];
            acc = __builtin_amdgcn_mfma_f32_16x16x32_bf16(a, bb, acc, 0, 0, 0);
            #pragma unroll
            for (int r = 0; r < 4; ++r)
                sc[mt * 16 + lr + r][nt * 16 + l15] = acc[r];
        }
        __syncthreads();
        // softmax rows (wave per row), add rel-bias + shift mask; write bf16 P (cols>=49 -> 0)
        for (int row = wave; row < 49; row += 4) {
            float v = -3.0e38f;
            if (lane < 49) {
                const int idx = row * 49 + lane;
                v = sc[row][lane] + rel_bias_table[rel_index[idx] * 3 + h] + maskrow[idx];
            }
            float mx = v;
            #pragma unroll
            for (int m = 1; m < 64; m <<= 1) mx = fmaxf(mx, __shfl_xor(mx, m));
            const float e = (lane < 49) ? __expf(v - mx) : 0.f;
            float ssum = e;
            #pragma unroll
            for (int m = 1; m < 64; m <<= 1) ssum += __shfl_xor(ssum, m);
            ps[row][lane] = f2b(e / ssum);
        }
        __syncthreads();
        // PV: out = P @ V  (64x64 @ 64x32), 4 Mt x 2 Nt tiles, K=64 (2 MFMA)
        for (int t = wave; t < 8; t += 4) {
            const int mt = t >> 1, nt = t & 1;
            f32x4 acc = {0.f, 0.f, 0.f, 0.f};
            #pragma unroll
            for (int ks2 = 0; ks2 < 2; ++ks2) {
                bf16x8 a  = *(const bf16x8*)&ps[mt * 16 + l15][ks2 * 32 + lk];
                bf16x8 bb = *(const bf16x8*)&vs[h * 32 + nt * 16 + l15][ks2 * 32 + lk];
                acc = __builtin_amdgcn_mfma_f32_16x16x32_bf16(a, bb, acc, 0, 0, 0);
            }
            #pragma unroll
            for (int r = 0; r < 4; ++r)
                xt[mt * 16 + lr + r][h * 32 + nt * 16 + l15] = f2b(acc[r]);
        }
        __syncthreads();
    }

    // ---- Phase 4: proj + residual + unshift scatter (64x96 @ 96x96), 4 Mt x 6 Nt ----
    for (int t = wave; t < 24; t += 4) {
        const int mt = t / 6, nt = t - 6 * mt;
        f32x4 acc = {0.f, 0.f, 0.f, 0.f};
        #pragma unroll
        for (int ksp = 0; ksp < 3; ++ksp) {
            bf16x8 a  = *(const bf16x8*)&xt[mt * 16 + l15][ksp * 32 + lk];
            bf16x8 bb = *(const bf16x8*)(wproj + (size_t)(nt * 16 + l15) * 96 + ksp * 32 + lk);
            acc = __builtin_amdgcn_mfma_f32_16x16x32_bf16(a, bb, acc, 0, 0, 0);
        }
        const int colf = nt * 16 + l15;
        const float pb = proj_b[colf];
        #pragma unroll
        for (int r = 0; r < 4; ++r) {
            const int n = mt * 16 + lr + r;
            if (n < 49) {
                const int p = n / 7, q = n - 7 * p;
                int sr = wi * 7 + p + 3;  if (sr >= 56) sr -= 56;
                int scl = wj * 7 + q + 3; if (scl >= 56) scl -= 56;
                const size_t base = ((size_t)b * 3136 + (size_t)(sr * 56 + scl)) * CDIM + colf;
                h_out[base] = acc[r] + pb + x[base];
            }
        }
    }
}

// ---------------- Kernel 2: LN2 + fc1 + GELU + fc2 + residual (MFMA, in-place on h) ----------------
__global__ __launch_bounds__(256) void swin_mlp_mfma(
    const float* __restrict__ ln2_g, const float* __restrict__ ln2_b,
    const float* __restrict__ fc1_b, const float* __restrict__ fc2_b,
    const unsigned short* __restrict__ wfc1,  // [384][96] bf16
    const unsigned short* __restrict__ wfc2,  // [96][384] bf16
    float* io)
{
    __shared__ unsigned short xs[64][104];   // LN2'd rows bf16
    __shared__ unsigned short m1[64][392];   // GELU(fc1) bf16

    const int tid = threadIdx.x, wave = tid >> 6, lane = tid & 63;
    const int l15 = lane & 15, lk = (lane >> 4) * 8, lr = (lane >> 4) * 4;
    const size_t r0 = (size_t)blockIdx.x * 64;

    // ---- LN2 ----
    for (int n = wave; n < 64; n += 4) {
        const float* xr = io + (r0 + n) * CDIM;
        float v0 = xr[lane];
        float v1 = (lane < 32) ? xr[64 + lane] : 0.f;
        float s = v0 + v1, ss2 = v0 * v0 + v1 * v1;
        #pragma unroll
        for (int m = 1; m < 64; m <<= 1) { s += __shfl_xor(s, m); ss2 += __shfl_xor(ss2, m); }
        const float mean = s * (1.f / 96.f);
        const float var  = ss2 * (1.f / 96.f) - mean * mean;
        const float rstd = rsqrtf(var + 1e-5f);
        xs[n][lane] = f2b((v0 - mean) * rstd * ln2_g[lane] + ln2_b[lane]);
        if (lane < 32)
            xs[n][64 + lane] = f2b((v1 - mean) * rstd * ln2_g[64 + lane] + ln2_b[64 + lane]);
    }
    __syncthreads();

    // ---- fc1 + exact GELU: 64x96 @ 96x384, 4 Mt x 24 Nt tiles ----
    for (int t = wave; t < 96; t += 4) {
        const int mt = t / 24, nt = t - 24 * mt;
        f32x4 acc = {0.f, 0.f, 0.f, 0.f};
        #pragma unroll
        for (int ksp = 0; ksp < 3; ++ksp) {
            bf16x8 a  = *(const bf16x8*)&xs[mt * 16 + l15][ksp * 32 + lk];
            bf16x8 bb = *(const bf16x8*)(wfc1 + (size_t)(nt * 16 + l15) * 96 + ksp * 32 + lk);
            acc = __builtin_amdgcn_mfma_f32_16x16x32_bf16(a, bb, acc, 0, 0, 0);
        }
        const int colf = nt * 16 + l15;
        const float b1 = fc1_b[colf];
        #pragma unroll
        for (int r = 0; r < 4; ++r) {
            const float u = acc[r] + b1;
            m1[mt * 16 + lr + r][colf] = f2b(0.5f * u * (1.f + erff(u * 0.70710678118654752f)));
        }
    }
    __syncthreads();

    // ---- fc2 + residual: 64x384 @ 384x96, 4 Mt x 6 Nt tiles, K=384 (12 MFMA) ----
    for (int t = wave; t < 24; t += 4) {
        const int mt = t / 6, nt = t - 6 * mt;
        f32x4 acc = {0.f, 0.f, 0.f, 0.f};
        #pragma unroll
        for (int ks = 0; ks < 12; ++ks) {
            bf16x8 a  = *(const bf16x8*)&m1[mt * 16 + l15][ks * 32 + lk];
            bf16x8 bb = *(const bf16x8*)(wfc2 + (size_t)(nt * 16 + l15) * 384 + ks * 32 + lk);
            acc = __builtin_amdgcn_mfma_f32_16x16x32_bf16(a, bb, acc, 0, 0, 0);
        }
        const int colf = nt * 16 + l15;
        const float b2 = fc2_b[colf];
        #pragma unroll
        for (int r = 0; r < 4; ++r) {
            const size_t o = (r0 + mt * 16 + lr + r) * CDIM + colf;
            io[o] = io[o] + acc[r] + b2;
        }
    }
}

extern "C" void kernel_launch(void* const* d_in, const int* in_sizes, int n_in,
                              void* d_out, int out_size, void* d_ws, size_t ws_size,
                              hipStream_t stream) {
    (void)n_in; (void)out_size; (void)ws_size;
    const float* x        = (const float*)d_in[0];
    const float* attn_msk = (const float*)d_in[1];
    const float* ln1_g    = (const float*)d_in[2];
    const float* ln1_b    = (const float*)d_in[3];
    const float* qkv_w    = (const float*)d_in[4];
    const float* qkv_b    = (const float*)d_in[5];
    const float* rel_tab  = (const float*)d_in[6];
    const int*   rel_idx  = (const int*)d_in[7];
    const float* proj_w   = (const float*)d_in[8];
    const float* proj_b   = (const float*)d_in[9];
    const float* ln2_g    = (const float*)d_in[10];
    const float* ln2_b    = (const float*)d_in[11];
    const float* fc1_w    = (const float*)d_in[12];
    const float* fc1_b    = (const float*)d_in[13];
    const float* fc2_w    = (const float*)d_in[14];
    const float* fc2_b    = (const float*)d_in[15];
    float* out = (float*)d_out;
    unsigned short* wsb = (unsigned short*)d_ws;

    const int B = in_sizes[0] / (3136 * 96);   // 64

    // bf16 weight staging (221 KB of ws)
    conv_w_kernel<<<(110592 + 255) / 256, 256, 0, stream>>>(qkv_w, proj_w, fc1_w, fc2_w, wsb);

    // h = x + attn(LN1(x))  -> d_out
    swin_attn_mfma<<<B * 64, 256, 0, stream>>>(
        x, attn_msk, ln1_g, ln1_b, qkv_b, rel_tab, rel_idx, proj_b,
        wsb, wsb + 27648, out);

    // out = h + MLP(LN2(h)) in-place
    swin_mlp_mfma<<<B * 49, 256, 0, stream>>>(
        ln2_g, ln2_b, fc1_b, fc2_b, wsb + 36864, wsb + 73728, out);
}

// Round 3
// 421.121 us; speedup vs baseline: 4.9446x; 1.6890x over previous
//
#include <hip/hip_runtime.h>
#include <math.h>

// Swin block, bf16-MFMA, barrier-lean attention.
// B=64, H=W=56, C=96, WS=7, SS=3, NH=3, HD=32, N=49 (padded 64), nW=64.

#define CDIM 96
#define SCALE_QK 0.17677669529663687f  // 32^-0.5

typedef __attribute__((ext_vector_type(8))) short bf16x8;
typedef __attribute__((ext_vector_type(4))) float f32x4;
typedef __attribute__((ext_vector_type(4))) unsigned int u32x4;

__device__ inline unsigned short f2b(float f) {
    union { float f; unsigned u; } v; v.f = f;
    unsigned r = v.u + 0x7FFF + ((v.u >> 16) & 1);   // RNE
    return (unsigned short)(r >> 16);
}
__device__ inline float b2f(unsigned short h) {
    union { unsigned u; float f; } v; v.u = ((unsigned)h) << 16;
    return v.f;
}
__device__ inline unsigned pk2(float a, float b) {
    return (unsigned)f2b(a) | ((unsigned)f2b(b) << 16);
}

// ---------------- Kernel 0a: weights fp32 -> bf16 ----------------
// ws shorts: qkv_w [288*96] @0, proj_w @27648, fc1_w @36864, fc2_w @73728, bm @110592
__global__ __launch_bounds__(256) void conv_w_kernel(
    const float* __restrict__ qkv_w, const float* __restrict__ proj_w,
    const float* __restrict__ fc1_w, const float* __restrict__ fc2_w,
    unsigned short* __restrict__ ws)
{
    const int i = blockIdx.x * 256 + threadIdx.x;
    if (i < 27648)       ws[i] = f2b(qkv_w[i]);
    else if (i < 36864)  ws[i] = f2b(proj_w[i - 27648]);
    else if (i < 73728)  ws[i] = f2b(fc1_w[i - 36864]);
    else if (i < 110592) ws[i] = f2b(fc2_w[i - 73728]);
}

// ---------------- Kernel 0b: fused rel-bias + shift-mask table ----------------
// bm[((widx*3+h)*64 + row)*64 + col], bf16; pad rows/cols -> -1e30
__global__ __launch_bounds__(256) void build_bm_kernel(
    const float* __restrict__ attn_mask, const float* __restrict__ rel_bias_table,
    const int* __restrict__ rel_index, unsigned short* __restrict__ bm)
{
    const int i = blockIdx.x * 256 + threadIdx.x;   // 786432 total
    const int col = i & 63, row = (i >> 6) & 63, t = i >> 12;  // t = widx*3+h
    const int h = t % 3, widx = t / 3;
    float v = -1.0e30f;
    if (row < 49 && col < 49) {
        const int idx = row * 49 + col;
        v = rel_bias_table[rel_index[idx] * 3 + h] + attn_mask[widx * 2401 + idx];
    }
    bm[i] = f2b(v);
}

// ---------------- Kernel 1: LN1 + shift + window attention + proj + residual ----------------
__global__ __launch_bounds__(256) void swin_attn_mfma(
    const float* __restrict__ x,
    const float* __restrict__ ln1_g, const float* __restrict__ ln1_b,
    const float* __restrict__ qkv_b, const float* __restrict__ proj_b,
    const unsigned short* __restrict__ wqkv,   // [288][96] bf16
    const unsigned short* __restrict__ wproj,  // [96][96] bf16
    const unsigned short* __restrict__ bm,     // [64][3][64][64] bf16
    float* __restrict__ h_out)
{
    __shared__ unsigned short xt[64][104];   // LN'd tokens; later attn-out
    __shared__ unsigned short qs[64][104];   // q
    __shared__ unsigned short kss[64][104];  // k
    __shared__ unsigned short vs[96][72];    // v transposed [feature][token]
    __shared__ unsigned short sc[3][64][72]; // scores -> probs (bf16, in place)

    const int w = blockIdx.x, b = w >> 6, widx = w & 63;
    const int wi = widx >> 3, wj = widx & 7;
    const int tid = threadIdx.x, wave = tid >> 6, lane = tid & 63;
    const int l15 = lane & 15, lk = (lane >> 4) * 8, lr = (lane >> 4) * 4;

    // ---- Phase 1: LN1 + shifted gather (roll -3,-3); quad (4 threads) per row ----
    {
        const int n = tid >> 2, q = tid & 3;
        if (n < 49) {
            const int p = n / 7, qq = n - 7 * p;
            int sr = wi * 7 + p + 3;  if (sr >= 56) sr -= 56;
            int scl = wj * 7 + qq + 3; if (scl >= 56) scl -= 56;
            const float* xr = x + ((size_t)b * 3136 + (size_t)(sr * 56 + scl)) * CDIM + q * 24;
            float vals[24];
            float s = 0.f, ss2 = 0.f;
            #pragma unroll
            for (int i = 0; i < 6; ++i) {
                const float4 f = *(const float4*)(xr + i * 4);
                vals[i*4+0] = f.x; vals[i*4+1] = f.y; vals[i*4+2] = f.z; vals[i*4+3] = f.w;
                s += f.x + f.y + f.z + f.w;
                ss2 += f.x*f.x + f.y*f.y + f.z*f.z + f.w*f.w;
            }
            s += __shfl_xor(s, 1);  ss2 += __shfl_xor(ss2, 1);
            s += __shfl_xor(s, 2);  ss2 += __shfl_xor(ss2, 2);
            const float mean = s * (1.f / 96.f);
            const float rstd = rsqrtf(ss2 * (1.f / 96.f) - mean * mean + 1e-5f);
            float o[24];
            #pragma unroll
            for (int i = 0; i < 24; ++i)
                o[i] = (vals[i] - mean) * rstd * ln1_g[q*24 + i] + ln1_b[q*24 + i];
            #pragma unroll
            for (int v8 = 0; v8 < 3; ++v8) {
                u32x4 pv;
                pv.x = pk2(o[v8*8+0], o[v8*8+1]);
                pv.y = pk2(o[v8*8+2], o[v8*8+3]);
                pv.z = pk2(o[v8*8+4], o[v8*8+5]);
                pv.w = pk2(o[v8*8+6], o[v8*8+7]);
                *(u32x4*)&xt[n][q*24 + v8*8] = pv;
            }
        } else {
            const u32x4 z = {0u, 0u, 0u, 0u};
            #pragma unroll
            for (int v8 = 0; v8 < 3; ++v8) *(u32x4*)&xt[n][q*24 + v8*8] = z;
        }
    }
    __syncthreads();

    // ---- Phase 2: qkv = xt @ Wqkv^T + b  (64x96 @ 96x288), 72 tiles ----
    for (int t = wave; t < 72; t += 4) {
        const int mt = t / 18, nt = t - 18 * mt;
        f32x4 acc = {0.f, 0.f, 0.f, 0.f};
        #pragma unroll
        for (int ksp = 0; ksp < 3; ++ksp) {
            bf16x8 a  = *(const bf16x8*)&xt[mt * 16 + l15][ksp * 32 + lk];
            bf16x8 bb = *(const bf16x8*)(wqkv + (size_t)(nt * 16 + l15) * 96 + ksp * 32 + lk);
            acc = __builtin_amdgcn_mfma_f32_16x16x32_bf16(a, bb, acc, 0, 0, 0);
        }
        const int colf = nt * 16 + l15;
        const float bias = qkv_b[colf];
        #pragma unroll
        for (int r = 0; r < 4; ++r) {
            const int rowt = mt * 16 + lr + r;
            const float vv = acc[r] + bias;
            if (colf < 96)       qs[rowt][colf] = f2b(vv * SCALE_QK);
            else if (colf < 192) kss[rowt][colf - 96] = f2b(vv);
            else                 vs[colf - 192][rowt] = f2b(vv);
        }
    }
    __syncthreads();

    // ---- Phase 3 (NO barriers): wave owns rows [16*wave, 16*wave+16) for all heads ----
    {
        const int mt = wave;
        const unsigned short* bmw = bm + (size_t)widx * 3 * 4096;
        for (int h = 0; h < 3; ++h) {
            // QK^T for this M-block: 4 N-tiles, K=32 (1 MFMA each); add bias; bf16 scores
            const bf16x8 a = *(const bf16x8*)&qs[mt * 16 + l15][h * 32 + lk];
            #pragma unroll
            for (int nt = 0; nt < 4; ++nt) {
                const bf16x8 bb = *(const bf16x8*)&kss[nt * 16 + l15][h * 32 + lk];
                f32x4 acc = {0.f, 0.f, 0.f, 0.f};
                acc = __builtin_amdgcn_mfma_f32_16x16x32_bf16(a, bb, acc, 0, 0, 0);
                const int col = nt * 16 + l15;
                #pragma unroll
                for (int r = 0; r < 4; ++r) {
                    const int row = mt * 16 + lr + r;
                    sc[h][row][col] = f2b(acc[r] + b2f(bmw[h * 4096 + row * 64 + col]));
                }
            }
            // softmax: quad per row (16 rows, 4 lanes each), in-place P (bf16)
            {
                const int rl = lane >> 2, q = lane & 3;
                const int row = mt * 16 + rl;
                const bf16x8 s0 = *(const bf16x8*)&sc[h][row][q * 16];
                const bf16x8 s1 = *(const bf16x8*)&sc[h][row][q * 16 + 8];
                float v[16];
                #pragma unroll
                for (int i = 0; i < 8; ++i) {
                    v[i]     = b2f((unsigned short)s0[i]);
                    v[8 + i] = b2f((unsigned short)s1[i]);
                }
                float mx = v[0];
                #pragma unroll
                for (int i = 1; i < 16; ++i) mx = fmaxf(mx, v[i]);
                mx = fmaxf(mx, __shfl_xor(mx, 1));
                mx = fmaxf(mx, __shfl_xor(mx, 2));
                float ssum = 0.f;
                #pragma unroll
                for (int i = 0; i < 16; ++i) { v[i] = __expf(v[i] - mx); ssum += v[i]; }
                ssum += __shfl_xor(ssum, 1);
                ssum += __shfl_xor(ssum, 2);
                const float inv = 1.0f / ssum;
                u32x4 p0, p1;
                p0.x = pk2(v[0]*inv,  v[1]*inv);  p0.y = pk2(v[2]*inv,  v[3]*inv);
                p0.z = pk2(v[4]*inv,  v[5]*inv);  p0.w = pk2(v[6]*inv,  v[7]*inv);
                p1.x = pk2(v[8]*inv,  v[9]*inv);  p1.y = pk2(v[10]*inv, v[11]*inv);
                p1.z = pk2(v[12]*inv, v[13]*inv); p1.w = pk2(v[14]*inv, v[15]*inv);
                *(u32x4*)&sc[h][row][q * 16]     = p0;
                *(u32x4*)&sc[h][row][q * 16 + 8] = p1;
            }
            // PV: O tile rows [16mt..), 2 d-halves, K=64 (2 MFMA)
            #pragma unroll
            for (int nt = 0; nt < 2; ++nt) {
                f32x4 o = {0.f, 0.f, 0.f, 0.f};
                #pragma unroll
                for (int c = 0; c < 2; ++c) {
                    const bf16x8 pa = *(const bf16x8*)&sc[h][mt * 16 + l15][c * 32 + lk];
                    const bf16x8 vb = *(const bf16x8*)&vs[h * 32 + nt * 16 + l15][c * 32 + lk];
                    o = __builtin_amdgcn_mfma_f32_16x16x32_bf16(pa, vb, o, 0, 0, 0);
                }
                #pragma unroll
                for (int r = 0; r < 4; ++r)
                    xt[mt * 16 + lr + r][h * 32 + nt * 16 + l15] = f2b(o[r]);
            }
        }
    }
    __syncthreads();

    // ---- Phase 4: proj + residual + unshift scatter (64x96 @ 96x96) ----
    for (int t = wave; t < 24; t += 4) {
        const int mt = t / 6, nt = t - 6 * mt;
        f32x4 acc = {0.f, 0.f, 0.f, 0.f};
        #pragma unroll
        for (int ksp = 0; ksp < 3; ++ksp) {
            bf16x8 a  = *(const bf16x8*)&xt[mt * 16 + l15][ksp * 32 + lk];
            bf16x8 bb = *(const bf16x8*)(wproj + (size_t)(nt * 16 + l15) * 96 + ksp * 32 + lk);
            acc = __builtin_amdgcn_mfma_f32_16x16x32_bf16(a, bb, acc, 0, 0, 0);
        }
        const int colf = nt * 16 + l15;
        const float pb = proj_b[colf];
        #pragma unroll
        for (int r = 0; r < 4; ++r) {
            const int n = mt * 16 + lr + r;
            if (n < 49) {
                const int p = n / 7, q = n - 7 * p;
                int sr = wi * 7 + p + 3;  if (sr >= 56) sr -= 56;
                int scl = wj * 7 + q + 3; if (scl >= 56) scl -= 56;
                const size_t base = ((size_t)b * 3136 + (size_t)(sr * 56 + scl)) * CDIM + colf;
                h_out[base] = acc[r] + pb + x[base];
            }
        }
    }
}

// ---------------- Kernel 2: LN2 + fc1 + GELU + fc2 + residual ----------------
__global__ __launch_bounds__(256) void swin_mlp_mfma(
    const float* __restrict__ ln2_g, const float* __restrict__ ln2_b,
    const float* __restrict__ fc1_b, const float* __restrict__ fc2_b,
    const unsigned short* __restrict__ wfc1,  // [384][96] bf16
    const unsigned short* __restrict__ wfc2,  // [96][384] bf16
    float* io)
{
    __shared__ unsigned short xs[64][104];
    __shared__ unsigned short m1[64][392];

    const int tid = threadIdx.x, wave = tid >> 6, lane = tid & 63;
    const int l15 = lane & 15, lk = (lane >> 4) * 8, lr = (lane >> 4) * 4;
    const size_t r0 = (size_t)blockIdx.x * 64;

    // ---- LN2: quad per row ----
    {
        const int n = tid >> 2, q = tid & 3;
        const float* xr = io + (r0 + n) * CDIM + q * 24;
        float vals[24];
        float s = 0.f, ss2 = 0.f;
        #pragma unroll
        for (int i = 0; i < 6; ++i) {
            const float4 f = *(const float4*)(xr + i * 4);
            vals[i*4+0] = f.x; vals[i*4+1] = f.y; vals[i*4+2] = f.z; vals[i*4+3] = f.w;
            s += f.x + f.y + f.z + f.w;
            ss2 += f.x*f.x + f.y*f.y + f.z*f.z + f.w*f.w;
        }
        s += __shfl_xor(s, 1);  ss2 += __shfl_xor(ss2, 1);
        s += __shfl_xor(s, 2);  ss2 += __shfl_xor(ss2, 2);
        const float mean = s * (1.f / 96.f);
        const float rstd = rsqrtf(ss2 * (1.f / 96.f) - mean * mean + 1e-5f);
        float o[24];
        #pragma unroll
        for (int i = 0; i < 24; ++i)
            o[i] = (vals[i] - mean) * rstd * ln2_g[q*24 + i] + ln2_b[q*24 + i];
        #pragma unroll
        for (int v8 = 0; v8 < 3; ++v8) {
            u32x4 pv;
            pv.x = pk2(o[v8*8+0], o[v8*8+1]);
            pv.y = pk2(o[v8*8+2], o[v8*8+3]);
            pv.z = pk2(o[v8*8+4], o[v8*8+5]);
            pv.w = pk2(o[v8*8+6], o[v8*8+7]);
            *(u32x4*)&xs[n][q*24 + v8*8] = pv;
        }
    }
    __syncthreads();

    // ---- fc1 + exact GELU: 64x96 @ 96x384 ----
    for (int t = wave; t < 96; t += 4) {
        const int mt = t / 24, nt = t - 24 * mt;
        f32x4 acc = {0.f, 0.f, 0.f, 0.f};
        #pragma unroll
        for (int ksp = 0; ksp < 3; ++ksp) {
            bf16x8 a  = *(const bf16x8*)&xs[mt * 16 + l15][ksp * 32 + lk];
            bf16x8 bb = *(const bf16x8*)(wfc1 + (size_t)(nt * 16 + l15) * 96 + ksp * 32 + lk);
            acc = __builtin_amdgcn_mfma_f32_16x16x32_bf16(a, bb, acc, 0, 0, 0);
        }
        const int colf = nt * 16 + l15;
        const float b1 = fc1_b[colf];
        #pragma unroll
        for (int r = 0; r < 4; ++r) {
            const float u = acc[r] + b1;
            m1[mt * 16 + lr + r][colf] = f2b(0.5f * u * (1.f + erff(u * 0.70710678118654752f)));
        }
    }
    __syncthreads();

    // ---- fc2 + residual: 64x384 @ 384x96 ----
    for (int t = wave; t < 24; t += 4) {
        const int mt = t / 6, nt = t - 6 * mt;
        f32x4 acc = {0.f, 0.f, 0.f, 0.f};
        #pragma unroll
        for (int ks = 0; ks < 12; ++ks) {
            bf16x8 a  = *(const bf16x8*)&m1[mt * 16 + l15][ks * 32 + lk];
            bf16x8 bb = *(const bf16x8*)(wfc2 + (size_t)(nt * 16 + l15) * 384 + ks * 32 + lk);
            acc = __builtin_amdgcn_mfma_f32_16x16x32_bf16(a, bb, acc, 0, 0, 0);
        }
        const int colf = nt * 16 + l15;
        const float b2 = fc2_b[colf];
        #pragma unroll
        for (int r = 0; r < 4; ++r) {
            const size_t o = (r0 + mt * 16 + lr + r) * CDIM + colf;
            io[o] = io[o] + acc[r] + b2;
        }
    }
}

extern "C" void kernel_launch(void* const* d_in, const int* in_sizes, int n_in,
                              void* d_out, int out_size, void* d_ws, size_t ws_size,
                              hipStream_t stream) {
    (void)n_in; (void)out_size; (void)ws_size;
    const float* x        = (const float*)d_in[0];
    const float* attn_msk = (const float*)d_in[1];
    const float* ln1_g    = (const float*)d_in[2];
    const float* ln1_b    = (const float*)d_in[3];
    const float* qkv_w    = (const float*)d_in[4];
    const float* qkv_b    = (const float*)d_in[5];
    const float* rel_tab  = (const float*)d_in[6];
    const int*   rel_idx  = (const int*)d_in[7];
    const float* proj_w   = (const float*)d_in[8];
    const float* proj_b   = (const float*)d_in[9];
    const float* ln2_g    = (const float*)d_in[10];
    const float* ln2_b    = (const float*)d_in[11];
    const float* fc1_w    = (const float*)d_in[12];
    const float* fc1_b    = (const float*)d_in[13];
    const float* fc2_w    = (const float*)d_in[14];
    const float* fc2_b    = (const float*)d_in[15];
    float* out = (float*)d_out;
    unsigned short* wsb = (unsigned short*)d_ws;

    const int B = in_sizes[0] / (3136 * 96);   // 64

    conv_w_kernel<<<(110592 + 255) / 256, 256, 0, stream>>>(qkv_w, proj_w, fc1_w, fc2_w, wsb);
    build_bm_kernel<<<786432 / 256, 256, 0, stream>>>(attn_msk, rel_tab, rel_idx, wsb + 110592);

    swin_attn_mfma<<<B * 64, 256, 0, stream>>>(
        x, ln1_g, ln1_b, qkv_b, proj_b,
        wsb, wsb + 27648, wsb + 110592, out);

    swin_mlp_mfma<<<B * 49, 256, 0, stream>>>(
        ln2_g, ln2_b, fc1_b, fc2_b, wsb + 36864, wsb + 73728, out);
}

// Round 4
// 344.385 us; speedup vs baseline: 6.0463x; 1.2228x over previous
//
#include <hip/hip_runtime.h>
#include <math.h>

// Swin block, bf16-MFMA, register softmax + fragment-layout bias tables.
// B=64, H=W=56, C=96, WS=7, SS=3, NH=3, HD=32, N=49 (padded 64), nW=64.

#define CDIM 96
#define SCALE_QK 0.17677669529663687f  // 32^-0.5
#define NW 8                            // waves per block

typedef __attribute__((ext_vector_type(8))) short bf16x8;
typedef __attribute__((ext_vector_type(4))) float f32x4;
typedef __attribute__((ext_vector_type(2))) unsigned int u32x2;

__device__ inline unsigned short f2b(float f) {
    union { float f; unsigned u; } v; v.f = f;
    unsigned r = v.u + 0x7FFF + ((v.u >> 16) & 1);   // RNE
    return (unsigned short)(r >> 16);
}
__device__ inline unsigned pk2(float a, float b) {
    return (unsigned)f2b(a) | ((unsigned)f2b(b) << 16);
}

// ---------------- Kernel 0a: weights fp32 -> bf16 ----------------
// ws shorts: qkv_w [288*96] @0, proj_w @27648, fc1_w @36864, fc2_w @73728 (end 110592)
// then bm_frag (f32) at short-offset 110592 (byte 221184), 786432 floats.
__global__ __launch_bounds__(256) void conv_w_kernel(
    const float* __restrict__ qkv_w, const float* __restrict__ proj_w,
    const float* __restrict__ fc1_w, const float* __restrict__ fc2_w,
    unsigned short* __restrict__ ws)
{
    const int i = blockIdx.x * 256 + threadIdx.x;
    if (i < 27648)       ws[i] = f2b(qkv_w[i]);
    else if (i < 36864)  ws[i] = f2b(proj_w[i - 27648]);
    else if (i < 73728)  ws[i] = f2b(fc1_w[i - 36864]);
    else if (i < 110592) ws[i] = f2b(fc2_w[i - 73728]);
}

// ---------------- Kernel 0b: bias+mask in MFMA C-fragment layout (swapped S') ----------------
// bmf[(((widx*3+h)*4 + kt)*4 + mt)*64 + lane] = f32x4 over rr.
// S'[k][q]: col(lane&15)=q-local, row=(lane>>4)*4+rr = k-local.
__global__ __launch_bounds__(256) void build_bmfrag_kernel(
    const float* __restrict__ attn_mask, const float* __restrict__ rel_bias_table,
    const int* __restrict__ rel_index, float* __restrict__ bmf)
{
    const int i = blockIdx.x * 256 + threadIdx.x;   // 196608 total
    const int lane = i & 63;
    const int mt = (i >> 6) & 3;
    const int kt = (i >> 8) & 3;
    const int t3 = i >> 10;                          // widx*3 + h
    const int h = t3 % 3, widx = t3 / 3;
    const int q = mt * 16 + (lane & 15);
    const int kb = kt * 16 + (lane >> 4) * 4;
    float4 v;
    float* vp = &v.x;
    #pragma unroll
    for (int rr = 0; rr < 4; ++rr) {
        const int k = kb + rr;
        float val = -1.0e30f;
        if (q < 49 && k < 49) {
            const int idx = q * 49 + k;
            val = rel_bias_table[rel_index[idx] * 3 + h] + attn_mask[widx * 2401 + idx];
        }
        vp[rr] = val;
    }
    *(float4*)(bmf + (size_t)i * 4) = v;
}

// ---------------- Kernel 1: LN1 + shift + window attention + proj + residual ----------------
__global__ __launch_bounds__(512, 4) void swin_attn_mfma(
    const float* __restrict__ x,
    const float* __restrict__ ln1_g, const float* __restrict__ ln1_b,
    const float* __restrict__ qkv_b, const float* __restrict__ proj_b,
    const unsigned short* __restrict__ wqkv,   // [288][96] bf16
    const unsigned short* __restrict__ wproj,  // [96][96] bf16
    const float* __restrict__ bmfrag,          // fragment-layout bias+mask
    float* __restrict__ h_out)
{
    __shared__ unsigned short xt[64][104];    // LN'd tokens; later attn-out [token][feat]
    __shared__ unsigned short qs[64][104];    // Q [token][feat] (scaled, +bias)
    __shared__ unsigned short kss[64][104];   // K [token][feat] (+bias)
    __shared__ unsigned short vs[96][72];     // V^T [feat][token] (+bias)
    __shared__ unsigned short ps[NW][16][72]; // per-wave P buffer [q-local][k]

    const int w = blockIdx.x, b = w >> 6, widx = w & 63;
    const int wi = widx >> 3, wj = widx & 7;
    const int tid = threadIdx.x, wave = tid >> 6, lane = tid & 63;
    const int l15 = lane & 15, lk = (lane >> 4) * 8, g4 = (lane >> 4) * 4;

    // ---- Phase 1: LN1 + shifted gather (roll -3,-3); 8 threads per row ----
    {
        const int n = tid >> 3, oc = tid & 7;
        if (n < 49) {
            const int p = n / 7, qq = n - 7 * p;
            int sr = wi * 7 + p + 3;   if (sr >= 56) sr -= 56;
            int scl = wj * 7 + qq + 3; if (scl >= 56) scl -= 56;
            const float* xr = x + ((size_t)b * 3136 + (size_t)(sr * 56 + scl)) * CDIM + oc * 12;
            float vals[12];
            float s = 0.f, ss2 = 0.f;
            #pragma unroll
            for (int i = 0; i < 3; ++i) {
                const float4 f = *(const float4*)(xr + i * 4);
                vals[i*4+0] = f.x; vals[i*4+1] = f.y; vals[i*4+2] = f.z; vals[i*4+3] = f.w;
                s += f.x + f.y + f.z + f.w;
                ss2 += f.x*f.x + f.y*f.y + f.z*f.z + f.w*f.w;
            }
            s += __shfl_xor(s, 1);  ss2 += __shfl_xor(ss2, 1);
            s += __shfl_xor(s, 2);  ss2 += __shfl_xor(ss2, 2);
            s += __shfl_xor(s, 4);  ss2 += __shfl_xor(ss2, 4);
            const float mean = s * (1.f / 96.f);
            const float rstd = rsqrtf(ss2 * (1.f / 96.f) - mean * mean + 1e-5f);
            #pragma unroll
            for (int v4 = 0; v4 < 3; ++v4) {
                const float4 gg = *(const float4*)(ln1_g + oc * 12 + v4 * 4);
                const float4 bb = *(const float4*)(ln1_b + oc * 12 + v4 * 4);
                u32x2 pv;
                pv.x = pk2((vals[v4*4+0]-mean)*rstd*gg.x + bb.x,
                           (vals[v4*4+1]-mean)*rstd*gg.y + bb.y);
                pv.y = pk2((vals[v4*4+2]-mean)*rstd*gg.z + bb.z,
                           (vals[v4*4+3]-mean)*rstd*gg.w + bb.w);
                *(u32x2*)&xt[n][oc * 12 + v4 * 4] = pv;
            }
        } else {
            const u32x2 z = {0u, 0u};
            #pragma unroll
            for (int v4 = 0; v4 < 3; ++v4) *(u32x2*)&xt[n][oc * 12 + v4 * 4] = z;
        }
    }
    __syncthreads();

    // ---- Phase 2: qkv projection, packed 8B stores ----
    // t<48: Q/K swapped GEMM  C[feat][token]  (12 feat-tiles x 4 token-tiles)
    // t>=48: V normal GEMM    C[token][vfeat] (4 token-tiles x 6 vfeat-tiles)
    for (int t = wave; t < 72; t += NW) {
        if (t < 48) {
            const int qt = t >> 2, ntt = t & 3;     // qt: feat-tile 0..11 (feats 0..191)
            f32x4 acc = {0.f, 0.f, 0.f, 0.f};
            #pragma unroll
            for (int ksp = 0; ksp < 3; ++ksp) {
                const bf16x8 a = *(const bf16x8*)(wqkv + (size_t)(qt * 16 + l15) * 96 + ksp * 32 + lk);
                const bf16x8 bx = *(const bf16x8*)&xt[ntt * 16 + l15][ksp * 32 + lk];
                acc = __builtin_amdgcn_mfma_f32_16x16x32_bf16(a, bx, acc, 0, 0, 0);
            }
            const int f0 = qt * 16 + g4;            // global feat base (0..188)
            const float4 bias = *(const float4*)(qkv_b + f0);
            const int tok = ntt * 16 + l15;
            u32x2 pw;
            if (qt < 6) {                            // Q (scale folded)
                pw.x = pk2((acc[0] + bias.x) * SCALE_QK, (acc[1] + bias.y) * SCALE_QK);
                pw.y = pk2((acc[2] + bias.z) * SCALE_QK, (acc[3] + bias.w) * SCALE_QK);
                *(u32x2*)&qs[tok][f0] = pw;
            } else {                                 // K
                pw.x = pk2(acc[0] + bias.x, acc[1] + bias.y);
                pw.y = pk2(acc[2] + bias.z, acc[3] + bias.w);
                *(u32x2*)&kss[tok][f0 - 96] = pw;
            }
        } else {
            const int u = t - 48, mtt = u / 6, vt = u - 6 * mtt;
            f32x4 acc = {0.f, 0.f, 0.f, 0.f};
            #pragma unroll
            for (int ksp = 0; ksp < 3; ++ksp) {
                const bf16x8 a = *(const bf16x8*)&xt[mtt * 16 + l15][ksp * 32 + lk];
                const bf16x8 bw = *(const bf16x8*)(wqkv + (size_t)(192 + vt * 16 + l15) * 96 + ksp * 32 + lk);
                acc = __builtin_amdgcn_mfma_f32_16x16x32_bf16(a, bw, acc, 0, 0, 0);
            }
            const float bias = qkv_b[192 + vt * 16 + l15];
            u32x2 pw;
            pw.x = pk2(acc[0] + bias, acc[1] + bias);
            pw.y = pk2(acc[2] + bias, acc[3] + bias);
            *(u32x2*)&vs[vt * 16 + l15][mtt * 16 + g4] = pw;
        }
    }
    __syncthreads();

    // ---- Phase 3 (no barriers): unit = (h, mt); swapped QK^T, register softmax, swapped PV ----
    for (int ui = wave; ui < 12; ui += NW) {
        const int h = ui >> 2, mt = ui & 3;
        const bf16x8 bq = *(const bf16x8*)&qs[mt * 16 + l15][h * 32 + lk];
        const float* bmb = bmfrag + ((((size_t)widx * 3 + h) * 4) * 4 + mt) * 64 * 4;
        f32x4 s[4];
        #pragma unroll
        for (int kt = 0; kt < 4; ++kt) {
            const bf16x8 ak = *(const bf16x8*)&kss[kt * 16 + l15][h * 32 + lk];
            const f32x4 c = *(const f32x4*)(bmb + ((size_t)kt * 4 * 64 + lane) * 4);
            s[kt] = __builtin_amdgcn_mfma_f32_16x16x32_bf16(ak, bq, c, 0, 0, 0);
        }
        // in-register softmax over the q-row (16 local + cross-group xor16/32: same q)
        float mx = s[0][0];
        #pragma unroll
        for (int kt = 0; kt < 4; ++kt)
            #pragma unroll
            for (int rr = 0; rr < 4; ++rr) mx = fmaxf(mx, s[kt][rr]);
        mx = fmaxf(mx, __shfl_xor(mx, 16));
        mx = fmaxf(mx, __shfl_xor(mx, 32));
        float sum = 0.f;
        #pragma unroll
        for (int kt = 0; kt < 4; ++kt)
            #pragma unroll
            for (int rr = 0; rr < 4; ++rr) {
                const float e = __expf(s[kt][rr] - mx);
                s[kt][rr] = e; sum += e;
            }
        sum += __shfl_xor(sum, 16);
        sum += __shfl_xor(sum, 32);
        const float inv = 1.0f / sum;
        #pragma unroll
        for (int kt = 0; kt < 4; ++kt) {
            u32x2 pw;
            pw.x = pk2(s[kt][0] * inv, s[kt][1] * inv);
            pw.y = pk2(s[kt][2] * inv, s[kt][3] * inv);
            *(u32x2*)&ps[wave][l15][kt * 16 + g4] = pw;
        }
        // PV swapped: C[d][q] = V^T P^T ; A = vs rows (d), B = ps rows (q)
        #pragma unroll
        for (int dt = 0; dt < 2; ++dt) {
            f32x4 o = {0.f, 0.f, 0.f, 0.f};
            #pragma unroll
            for (int c2 = 0; c2 < 2; ++c2) {
                const bf16x8 va = *(const bf16x8*)&vs[h * 32 + dt * 16 + l15][c2 * 32 + lk];
                const bf16x8 pa = *(const bf16x8*)&ps[wave][l15][c2 * 32 + lk];
                o = __builtin_amdgcn_mfma_f32_16x16x32_bf16(va, pa, o, 0, 0, 0);
            }
            u32x2 ow;
            ow.x = pk2(o[0], o[1]);
            ow.y = pk2(o[2], o[3]);
            *(u32x2*)&xt[mt * 16 + l15][h * 32 + dt * 16 + g4] = ow;
        }
    }
    __syncthreads();

    // ---- Phase 4: proj + residual + unshift scatter (64x96 @ 96x96) ----
    for (int t = wave; t < 24; t += NW) {
        const int mt = t / 6, nt = t - 6 * mt;
        f32x4 acc = {0.f, 0.f, 0.f, 0.f};
        #pragma unroll
        for (int ksp = 0; ksp < 3; ++ksp) {
            const bf16x8 a  = *(const bf16x8*)&xt[mt * 16 + l15][ksp * 32 + lk];
            const bf16x8 bb = *(const bf16x8*)(wproj + (size_t)(nt * 16 + l15) * 96 + ksp * 32 + lk);
            acc = __builtin_amdgcn_mfma_f32_16x16x32_bf16(a, bb, acc, 0, 0, 0);
        }
        const int colf = nt * 16 + l15;
        const float pb = proj_b[colf];
        #pragma unroll
        for (int rr = 0; rr < 4; ++rr) {
            const int n = mt * 16 + g4 + rr;
            if (n < 49) {
                const int p = n / 7, q = n - 7 * p;
                int sr = wi * 7 + p + 3;  if (sr >= 56) sr -= 56;
                int scl = wj * 7 + q + 3; if (scl >= 56) scl -= 56;
                const size_t base = ((size_t)b * 3136 + (size_t)(sr * 56 + scl)) * CDIM + colf;
                h_out[base] = acc[rr] + pb + x[base];
            }
        }
    }
}

// ---------------- Kernel 2: LN2 + fc1 + GELU + fc2 + residual ----------------
__global__ __launch_bounds__(512, 4) void swin_mlp_mfma(
    const float* __restrict__ ln2_g, const float* __restrict__ ln2_b,
    const float* __restrict__ fc1_b, const float* __restrict__ fc2_b,
    const unsigned short* __restrict__ wfc1,  // [384][96] bf16
    const unsigned short* __restrict__ wfc2,  // [96][384] bf16
    float* io)
{
    __shared__ unsigned short xs[64][104];
    __shared__ unsigned short m1[64][392];

    const int tid = threadIdx.x, wave = tid >> 6, lane = tid & 63;
    const int l15 = lane & 15, lk = (lane >> 4) * 8, g4 = (lane >> 4) * 4;
    const size_t r0 = (size_t)blockIdx.x * 64;

    // ---- LN2: 8 threads per row ----
    {
        const int n = tid >> 3, oc = tid & 7;
        const float* xr = io + (r0 + n) * CDIM + oc * 12;
        float vals[12];
        float s = 0.f, ss2 = 0.f;
        #pragma unroll
        for (int i = 0; i < 3; ++i) {
            const float4 f = *(const float4*)(xr + i * 4);
            vals[i*4+0] = f.x; vals[i*4+1] = f.y; vals[i*4+2] = f.z; vals[i*4+3] = f.w;
            s += f.x + f.y + f.z + f.w;
            ss2 += f.x*f.x + f.y*f.y + f.z*f.z + f.w*f.w;
        }
        s += __shfl_xor(s, 1);  ss2 += __shfl_xor(ss2, 1);
        s += __shfl_xor(s, 2);  ss2 += __shfl_xor(ss2, 2);
        s += __shfl_xor(s, 4);  ss2 += __shfl_xor(ss2, 4);
        const float mean = s * (1.f / 96.f);
        const float rstd = rsqrtf(ss2 * (1.f / 96.f) - mean * mean + 1e-5f);
        #pragma unroll
        for (int v4 = 0; v4 < 3; ++v4) {
            const float4 gg = *(const float4*)(ln2_g + oc * 12 + v4 * 4);
            const float4 bb = *(const float4*)(ln2_b + oc * 12 + v4 * 4);
            u32x2 pv;
            pv.x = pk2((vals[v4*4+0]-mean)*rstd*gg.x + bb.x,
                       (vals[v4*4+1]-mean)*rstd*gg.y + bb.y);
            pv.y = pk2((vals[v4*4+2]-mean)*rstd*gg.z + bb.z,
                       (vals[v4*4+3]-mean)*rstd*gg.w + bb.w);
            *(u32x2*)&xs[n][oc * 12 + v4 * 4] = pv;
        }
    }
    __syncthreads();

    // ---- fc1 + exact GELU, swapped GEMM: C[feat][token], packed stores ----
    for (int t = wave; t < 96; t += NW) {
        const int ft = t >> 2, ntt = t & 3;      // ft 0..23 (384 feats), ntt token-tile
        f32x4 acc = {0.f, 0.f, 0.f, 0.f};
        #pragma unroll
        for (int ksp = 0; ksp < 3; ++ksp) {
            const bf16x8 a = *(const bf16x8*)(wfc1 + (size_t)(ft * 16 + l15) * 96 + ksp * 32 + lk);
            const bf16x8 bx = *(const bf16x8*)&xs[ntt * 16 + l15][ksp * 32 + lk];
            acc = __builtin_amdgcn_mfma_f32_16x16x32_bf16(a, bx, acc, 0, 0, 0);
        }
        const int f0 = ft * 16 + g4;
        const float4 bias = *(const float4*)(fc1_b + f0);
        const float* bp = &bias.x;
        float g[4];
        #pragma unroll
        for (int rr = 0; rr < 4; ++rr) {
            const float u = acc[rr] + bp[rr];
            g[rr] = 0.5f * u * (1.f + erff(u * 0.70710678118654752f));
        }
        u32x2 pw;
        pw.x = pk2(g[0], g[1]);
        pw.y = pk2(g[2], g[3]);
        *(u32x2*)&m1[ntt * 16 + l15][f0] = pw;
    }
    __syncthreads();

    // ---- fc2 + residual: 64x384 @ 384x96 ----
    for (int t = wave; t < 24; t += NW) {
        const int mt2 = t / 6, nt2 = t - 6 * mt2;
        f32x4 acc = {0.f, 0.f, 0.f, 0.f};
        #pragma unroll
        for (int ks = 0; ks < 12; ++ks) {
            const bf16x8 a  = *(const bf16x8*)&m1[mt2 * 16 + l15][ks * 32 + lk];
            const bf16x8 bb = *(const bf16x8*)(wfc2 + (size_t)(nt2 * 16 + l15) * 384 + ks * 32 + lk);
            acc = __builtin_amdgcn_mfma_f32_16x16x32_bf16(a, bb, acc, 0, 0, 0);
        }
        const int colf = nt2 * 16 + l15;
        const float b2 = fc2_b[colf];
        #pragma unroll
        for (int rr = 0; rr < 4; ++rr) {
            const size_t o = (r0 + mt2 * 16 + g4 + rr) * CDIM + colf;
            io[o] = io[o] + acc[rr] + b2;
        }
    }
}

extern "C" void kernel_launch(void* const* d_in, const int* in_sizes, int n_in,
                              void* d_out, int out_size, void* d_ws, size_t ws_size,
                              hipStream_t stream) {
    (void)n_in; (void)out_size; (void)ws_size;
    const float* x        = (const float*)d_in[0];
    const float* attn_msk = (const float*)d_in[1];
    const float* ln1_g    = (const float*)d_in[2];
    const float* ln1_b    = (const float*)d_in[3];
    const float* qkv_w    = (const float*)d_in[4];
    const float* qkv_b    = (const float*)d_in[5];
    const float* rel_tab  = (const float*)d_in[6];
    const int*   rel_idx  = (const int*)d_in[7];
    const float* proj_w   = (const float*)d_in[8];
    const float* proj_b   = (const float*)d_in[9];
    const float* ln2_g    = (const float*)d_in[10];
    const float* ln2_b    = (const float*)d_in[11];
    const float* fc1_w    = (const float*)d_in[12];
    const float* fc1_b    = (const float*)d_in[13];
    const float* fc2_w    = (const float*)d_in[14];
    const float* fc2_b    = (const float*)d_in[15];
    float* out = (float*)d_out;
    unsigned short* wsb = (unsigned short*)d_ws;
    float* bmf = (float*)(wsb + 110592);

    const int B = in_sizes[0] / (3136 * 96);   // 64

    conv_w_kernel<<<(110592 + 255) / 256, 256, 0, stream>>>(qkv_w, proj_w, fc1_w, fc2_w, wsb);
    build_bmfrag_kernel<<<196608 / 256, 256, 0, stream>>>(attn_msk, rel_tab, rel_idx, bmf);

    swin_attn_mfma<<<B * 64, 512, 0, stream>>>(
        x, ln1_g, ln1_b, qkv_b, proj_b,
        wsb, wsb + 27648, bmf, out);

    swin_mlp_mfma<<<B * 49, 512, 0, stream>>>(
        ln2_g, ln2_b, fc1_b, fc2_b, wsb + 36864, wsb + 73728, out);
}

// Round 5
// 335.624 us; speedup vs baseline: 6.2042x; 1.0261x over previous
//
#include <hip/hip_runtime.h>
#include <math.h>

// Swin block, bf16-MFMA, static-unrolled loops, 128-token MLP blocks.
// B=64, H=W=56, C=96, WS=7, SS=3, NH=3, HD=32, N=49 (padded 64), nW=64.

#define CDIM 96
#define SCALE_QK 0.17677669529663687f  // 32^-0.5
#define NW 8                            // waves per attn block

typedef __attribute__((ext_vector_type(8))) short bf16x8;
typedef __attribute__((ext_vector_type(4))) float f32x4;
typedef __attribute__((ext_vector_type(2))) unsigned int u32x2;

__device__ inline unsigned short f2b(float f) {
    union { float f; unsigned u; } v; v.f = f;
    unsigned r = v.u + 0x7FFF + ((v.u >> 16) & 1);   // RNE
    return (unsigned short)(r >> 16);
}
__device__ inline unsigned pk2(float a, float b) {
    return (unsigned)f2b(a) | ((unsigned)f2b(b) << 16);
}
__device__ inline float bitsf(unsigned u) {
    union { unsigned u; float f; } v; v.u = u; return v.f;
}

// ---------------- Kernel 0a: weights fp32 -> bf16 ----------------
// ws shorts: qkv_w [288*96] @0, proj_w @27648, fc1_w @36864, fc2_w @73728 (end 110592),
// bm_frag bf16 @110592 (786432 shorts).
__global__ __launch_bounds__(256) void conv_w_kernel(
    const float* __restrict__ qkv_w, const float* __restrict__ proj_w,
    const float* __restrict__ fc1_w, const float* __restrict__ fc2_w,
    unsigned short* __restrict__ ws)
{
    const int i = blockIdx.x * 256 + threadIdx.x;
    if (i < 27648)       ws[i] = f2b(qkv_w[i]);
    else if (i < 36864)  ws[i] = f2b(proj_w[i - 27648]);
    else if (i < 73728)  ws[i] = f2b(fc1_w[i - 36864]);
    else if (i < 110592) ws[i] = f2b(fc2_w[i - 73728]);
}

// ---------------- Kernel 0b: bias+mask in MFMA C-fragment layout, bf16 ----------------
// bmf[(((widx*3+h)*4 + kt)*4 + mt)*64 + lane] -> 4 bf16 (rr = 0..3).
// S'[k][q]: col(lane&15)=q-local, row=(lane>>4)*4+rr = k-local.
__global__ __launch_bounds__(256) void build_bmfrag_kernel(
    const float* __restrict__ attn_mask, const float* __restrict__ rel_bias_table,
    const int* __restrict__ rel_index, unsigned short* __restrict__ bmf)
{
    const int i = blockIdx.x * 256 + threadIdx.x;   // 196608 total
    const int lane = i & 63;
    const int mt = (i >> 6) & 3;
    const int kt = (i >> 8) & 3;
    const int t3 = i >> 10;                          // widx*3 + h
    const int h = t3 % 3, widx = t3 / 3;
    const int q = mt * 16 + (lane & 15);
    const int kb = kt * 16 + (lane >> 4) * 4;
    float vv[4];
    #pragma unroll
    for (int rr = 0; rr < 4; ++rr) {
        const int k = kb + rr;
        float val = -1.0e30f;
        if (q < 49 && k < 49) {
            const int idx = q * 49 + k;
            val = rel_bias_table[rel_index[idx] * 3 + h] + attn_mask[widx * 2401 + idx];
        }
        vv[rr] = val;
    }
    u32x2 pw;
    pw.x = pk2(vv[0], vv[1]);
    pw.y = pk2(vv[2], vv[3]);
    *(u32x2*)(bmf + (size_t)i * 4) = pw;
}

// ---------------- Kernel 1: LN1 + shift + window attention + proj + residual ----------------
__global__ __launch_bounds__(512, 4) void swin_attn_mfma(
    const float* __restrict__ x,
    const float* __restrict__ ln1_g, const float* __restrict__ ln1_b,
    const float* __restrict__ qkv_b, const float* __restrict__ proj_b,
    const unsigned short* __restrict__ wqkv,   // [288][96] bf16
    const unsigned short* __restrict__ wproj,  // [96][96] bf16
    const unsigned short* __restrict__ bmfrag, // fragment-layout bias+mask, bf16
    float* __restrict__ h_out)
{
    __shared__ unsigned short xt[64][104];    // LN'd tokens; later attn-out [token][feat]
    __shared__ unsigned short qs[64][104];    // Q [token][feat] (scaled, +bias)
    __shared__ unsigned short kss[64][104];   // K [token][feat] (+bias)
    __shared__ unsigned short vs[96][72];     // V^T [feat][token] (+bias)
    __shared__ unsigned short ps[NW][16][72]; // per-wave P buffer [q-local][k]

    const int w = blockIdx.x, b = w >> 6, widx = w & 63;
    const int wi = widx >> 3, wj = widx & 7;
    const int tid = threadIdx.x, wave = tid >> 6, lane = tid & 63;
    const int l15 = lane & 15, lk = (lane >> 4) * 8, g4 = (lane >> 4) * 4;

    // ---- Phase 1: LN1 + shifted gather (roll -3,-3); 8 threads per row ----
    {
        const int n = tid >> 3, oc = tid & 7;
        if (n < 49) {
            const int p = n / 7, qq = n - 7 * p;
            int sr = wi * 7 + p + 3;   if (sr >= 56) sr -= 56;
            int scl = wj * 7 + qq + 3; if (scl >= 56) scl -= 56;
            const float* xr = x + ((size_t)b * 3136 + (size_t)(sr * 56 + scl)) * CDIM + oc * 12;
            float vals[12];
            float s = 0.f, ss2 = 0.f;
            #pragma unroll
            for (int i = 0; i < 3; ++i) {
                const float4 f = *(const float4*)(xr + i * 4);
                vals[i*4+0] = f.x; vals[i*4+1] = f.y; vals[i*4+2] = f.z; vals[i*4+3] = f.w;
                s += f.x + f.y + f.z + f.w;
                ss2 += f.x*f.x + f.y*f.y + f.z*f.z + f.w*f.w;
            }
            s += __shfl_xor(s, 1);  ss2 += __shfl_xor(ss2, 1);
            s += __shfl_xor(s, 2);  ss2 += __shfl_xor(ss2, 2);
            s += __shfl_xor(s, 4);  ss2 += __shfl_xor(ss2, 4);
            const float mean = s * (1.f / 96.f);
            const float rstd = rsqrtf(ss2 * (1.f / 96.f) - mean * mean + 1e-5f);
            #pragma unroll
            for (int v4 = 0; v4 < 3; ++v4) {
                const float4 gg = *(const float4*)(ln1_g + oc * 12 + v4 * 4);
                const float4 bb = *(const float4*)(ln1_b + oc * 12 + v4 * 4);
                u32x2 pv;
                pv.x = pk2((vals[v4*4+0]-mean)*rstd*gg.x + bb.x,
                           (vals[v4*4+1]-mean)*rstd*gg.y + bb.y);
                pv.y = pk2((vals[v4*4+2]-mean)*rstd*gg.z + bb.z,
                           (vals[v4*4+3]-mean)*rstd*gg.w + bb.w);
                *(u32x2*)&xt[n][oc * 12 + v4 * 4] = pv;
            }
        } else {
            const u32x2 z = {0u, 0u};
            #pragma unroll
            for (int v4 = 0; v4 < 3; ++v4) *(u32x2*)&xt[n][oc * 12 + v4 * 4] = z;
        }
    }
    __syncthreads();

    // ---- Phase 2: qkv projection, static 9 iters/wave, packed 8B stores ----
    #pragma unroll
    for (int i = 0; i < 9; ++i) {
        const int t = wave + 8 * i;
        if (t < 48) {
            const int qt = t >> 2, ntt = t & 3;     // ntt const per wave -> bx hoisted
            f32x4 acc = {0.f, 0.f, 0.f, 0.f};
            #pragma unroll
            for (int ksp = 0; ksp < 3; ++ksp) {
                const bf16x8 a = *(const bf16x8*)(wqkv + (size_t)(qt * 16 + l15) * 96 + ksp * 32 + lk);
                const bf16x8 bx = *(const bf16x8*)&xt[ntt * 16 + l15][ksp * 32 + lk];
                acc = __builtin_amdgcn_mfma_f32_16x16x32_bf16(a, bx, acc, 0, 0, 0);
            }
            const int f0 = qt * 16 + g4;
            const float4 bias = *(const float4*)(qkv_b + f0);
            const int tok = ntt * 16 + l15;
            u32x2 pw;
            if (qt < 6) {                            // Q (scale folded)
                pw.x = pk2((acc[0] + bias.x) * SCALE_QK, (acc[1] + bias.y) * SCALE_QK);
                pw.y = pk2((acc[2] + bias.z) * SCALE_QK, (acc[3] + bias.w) * SCALE_QK);
                *(u32x2*)&qs[tok][f0] = pw;
            } else {                                 // K
                pw.x = pk2(acc[0] + bias.x, acc[1] + bias.y);
                pw.y = pk2(acc[2] + bias.z, acc[3] + bias.w);
                *(u32x2*)&kss[tok][f0 - 96] = pw;
            }
        } else {
            const int u = t - 48, mtt = u / 6, vt = u - 6 * mtt;
            f32x4 acc = {0.f, 0.f, 0.f, 0.f};
            #pragma unroll
            for (int ksp = 0; ksp < 3; ++ksp) {
                const bf16x8 a = *(const bf16x8*)&xt[mtt * 16 + l15][ksp * 32 + lk];
                const bf16x8 bw = *(const bf16x8*)(wqkv + (size_t)(192 + vt * 16 + l15) * 96 + ksp * 32 + lk);
                acc = __builtin_amdgcn_mfma_f32_16x16x32_bf16(a, bw, acc, 0, 0, 0);
            }
            const float bias = qkv_b[192 + vt * 16 + l15];
            u32x2 pw;
            pw.x = pk2(acc[0] + bias, acc[1] + bias);
            pw.y = pk2(acc[2] + bias, acc[3] + bias);
            *(u32x2*)&vs[vt * 16 + l15][mtt * 16 + g4] = pw;
        }
    }
    __syncthreads();

    // ---- Phase 3 (no barriers): unit = (h, mt); swapped QK^T, register softmax, swapped PV ----
    #pragma unroll
    for (int it = 0; it < 2; ++it) {
        const int ui = wave + 8 * it;
        if (ui < 12) {
            const int h = ui >> 2, mt = ui & 3;
            const bf16x8 bq = *(const bf16x8*)&qs[mt * 16 + l15][h * 32 + lk];
            const unsigned short* bmb = bmfrag + ((((size_t)widx * 3 + h) * 4) * 4 + mt) * 64 * 4;
            f32x4 s[4];
            #pragma unroll
            for (int kt = 0; kt < 4; ++kt) {
                const bf16x8 ak = *(const bf16x8*)&kss[kt * 16 + l15][h * 32 + lk];
                const u32x2 cw = *(const u32x2*)(bmb + ((size_t)kt * 4 * 64 + lane) * 4);
                f32x4 c;
                c[0] = bitsf(cw.x << 16); c[1] = bitsf(cw.x & 0xffff0000u);
                c[2] = bitsf(cw.y << 16); c[3] = bitsf(cw.y & 0xffff0000u);
                s[kt] = __builtin_amdgcn_mfma_f32_16x16x32_bf16(ak, bq, c, 0, 0, 0);
            }
            // in-register softmax over the q-row
            float mx = s[0][0];
            #pragma unroll
            for (int kt = 0; kt < 4; ++kt)
                #pragma unroll
                for (int rr = 0; rr < 4; ++rr) mx = fmaxf(mx, s[kt][rr]);
            mx = fmaxf(mx, __shfl_xor(mx, 16));
            mx = fmaxf(mx, __shfl_xor(mx, 32));
            float sum = 0.f;
            #pragma unroll
            for (int kt = 0; kt < 4; ++kt)
                #pragma unroll
                for (int rr = 0; rr < 4; ++rr) {
                    const float e = __expf(s[kt][rr] - mx);
                    s[kt][rr] = e; sum += e;
                }
            sum += __shfl_xor(sum, 16);
            sum += __shfl_xor(sum, 32);
            const float inv = 1.0f / sum;
            #pragma unroll
            for (int kt = 0; kt < 4; ++kt) {
                u32x2 pw;
                pw.x = pk2(s[kt][0] * inv, s[kt][1] * inv);
                pw.y = pk2(s[kt][2] * inv, s[kt][3] * inv);
                *(u32x2*)&ps[wave][l15][kt * 16 + g4] = pw;
            }
            // PV swapped: C[d][q]; A = vs rows (d), B = ps rows (q)
            #pragma unroll
            for (int dt = 0; dt < 2; ++dt) {
                f32x4 o = {0.f, 0.f, 0.f, 0.f};
                #pragma unroll
                for (int c2 = 0; c2 < 2; ++c2) {
                    const bf16x8 va = *(const bf16x8*)&vs[h * 32 + dt * 16 + l15][c2 * 32 + lk];
                    const bf16x8 pa = *(const bf16x8*)&ps[wave][l15][c2 * 32 + lk];
                    o = __builtin_amdgcn_mfma_f32_16x16x32_bf16(va, pa, o, 0, 0, 0);
                }
                u32x2 ow;
                ow.x = pk2(o[0], o[1]);
                ow.y = pk2(o[2], o[3]);
                *(u32x2*)&xt[mt * 16 + l15][h * 32 + dt * 16 + g4] = ow;
            }
        }
    }
    __syncthreads();

    // ---- Phase 4: proj + residual + unshift scatter (64x96 @ 96x96), static 3 iters ----
    #pragma unroll
    for (int i = 0; i < 3; ++i) {
        const int t = wave + 8 * i;
        const int mt = t / 6, nt = t - 6 * mt;
        f32x4 acc = {0.f, 0.f, 0.f, 0.f};
        #pragma unroll
        for (int ksp = 0; ksp < 3; ++ksp) {
            const bf16x8 a  = *(const bf16x8*)&xt[mt * 16 + l15][ksp * 32 + lk];
            const bf16x8 bb = *(const bf16x8*)(wproj + (size_t)(nt * 16 + l15) * 96 + ksp * 32 + lk);
            acc = __builtin_amdgcn_mfma_f32_16x16x32_bf16(a, bb, acc, 0, 0, 0);
        }
        const int colf = nt * 16 + l15;
        const float pb = proj_b[colf];
        #pragma unroll
        for (int rr = 0; rr < 4; ++rr) {
            const int n = mt * 16 + g4 + rr;
            if (n < 49) {
                const int p = n / 7, q = n - 7 * p;
                int sr = wi * 7 + p + 3;  if (sr >= 56) sr -= 56;
                int scl = wj * 7 + q + 3; if (scl >= 56) scl -= 56;
                const size_t base = ((size_t)b * 3136 + (size_t)(sr * 56 + scl)) * CDIM + colf;
                h_out[base] = acc[rr] + pb + x[base];
            }
        }
    }
}

// ---------------- Kernel 2: LN2 + fc1 + GELU + fc2 + residual (128 tokens/block) ----------------
__global__ __launch_bounds__(1024, 4) void swin_mlp_mfma(
    const float* __restrict__ ln2_g, const float* __restrict__ ln2_b,
    const float* __restrict__ fc1_b, const float* __restrict__ fc2_b,
    const unsigned short* __restrict__ wfc1,  // [384][96] bf16
    const unsigned short* __restrict__ wfc2,  // [96][384] bf16
    float* io)
{
    __shared__ unsigned short xs[128][104];
    __shared__ unsigned short m1[128][392];

    const int tid = threadIdx.x, wave = tid >> 6, lane = tid & 63;
    const int l15 = lane & 15, lk = (lane >> 4) * 8, g4 = (lane >> 4) * 4;
    const size_t r0 = (size_t)blockIdx.x * 128;

    // ---- LN2: 8 threads per row, 128 rows ----
    {
        const int n = tid >> 3, oc = tid & 7;
        const float* xr = io + (r0 + n) * CDIM + oc * 12;
        float vals[12];
        float s = 0.f, ss2 = 0.f;
        #pragma unroll
        for (int i = 0; i < 3; ++i) {
            const float4 f = *(const float4*)(xr + i * 4);
            vals[i*4+0] = f.x; vals[i*4+1] = f.y; vals[i*4+2] = f.z; vals[i*4+3] = f.w;
            s += f.x + f.y + f.z + f.w;
            ss2 += f.x*f.x + f.y*f.y + f.z*f.z + f.w*f.w;
        }
        s += __shfl_xor(s, 1);  ss2 += __shfl_xor(ss2, 1);
        s += __shfl_xor(s, 2);  ss2 += __shfl_xor(ss2, 2);
        s += __shfl_xor(s, 4);  ss2 += __shfl_xor(ss2, 4);
        const float mean = s * (1.f / 96.f);
        const float rstd = rsqrtf(ss2 * (1.f / 96.f) - mean * mean + 1e-5f);
        #pragma unroll
        for (int v4 = 0; v4 < 3; ++v4) {
            const float4 gg = *(const float4*)(ln2_g + oc * 12 + v4 * 4);
            const float4 bb = *(const float4*)(ln2_b + oc * 12 + v4 * 4);
            u32x2 pv;
            pv.x = pk2((vals[v4*4+0]-mean)*rstd*gg.x + bb.x,
                       (vals[v4*4+1]-mean)*rstd*gg.y + bb.y);
            pv.y = pk2((vals[v4*4+2]-mean)*rstd*gg.z + bb.z,
                       (vals[v4*4+3]-mean)*rstd*gg.w + bb.w);
            *(u32x2*)&xs[n][oc * 12 + v4 * 4] = pv;
        }
    }
    __syncthreads();

    // ---- fc1 + tanh-GELU, swapped GEMM C[feat][token], static 12 iters/wave ----
    #pragma unroll
    for (int i = 0; i < 12; ++i) {
        const int t = wave + 16 * i;
        const int ft = t >> 3, ntt = t & 7;      // ntt const per wave -> bx hoisted
        f32x4 acc = {0.f, 0.f, 0.f, 0.f};
        #pragma unroll
        for (int ksp = 0; ksp < 3; ++ksp) {
            const bf16x8 a = *(const bf16x8*)(wfc1 + (size_t)(ft * 16 + l15) * 96 + ksp * 32 + lk);
            const bf16x8 bx = *(const bf16x8*)&xs[ntt * 16 + l15][ksp * 32 + lk];
            acc = __builtin_amdgcn_mfma_f32_16x16x32_bf16(a, bx, acc, 0, 0, 0);
        }
        const int f0 = ft * 16 + g4;
        const float4 bias = *(const float4*)(fc1_b + f0);
        const float* bp = &bias.x;
        float g[4];
        #pragma unroll
        for (int rr = 0; rr < 4; ++rr) {
            const float u = acc[rr] + bp[rr];
            // gelu(u) = u * 0.5*(1+tanh(y)) = u / (1 + exp(-2y)), y = 0.79788456*(u + 0.044715 u^3)
            const float u2 = u * u;
            const float n2y = u * (-1.5957691216f - 0.0713548162f * u2);
            g[rr] = __fdividef(u, 1.f + __expf(n2y));
        }
        u32x2 pw;
        pw.x = pk2(g[0], g[1]);
        pw.y = pk2(g[2], g[3]);
        *(u32x2*)&m1[ntt * 16 + l15][f0] = pw;
    }
    __syncthreads();

    // ---- fc2 + residual: 128x384 @ 384x96, static 3 iters/wave ----
    #pragma unroll
    for (int i = 0; i < 3; ++i) {
        const int t = wave + 16 * i;
        const int mt2 = t / 6, nt2 = t - 6 * mt2;
        f32x4 acc = {0.f, 0.f, 0.f, 0.f};
        #pragma unroll
        for (int ks = 0; ks < 12; ++ks) {
            const bf16x8 a  = *(const bf16x8*)&m1[mt2 * 16 + l15][ks * 32 + lk];
            const bf16x8 bb = *(const bf16x8*)(wfc2 + (size_t)(nt2 * 16 + l15) * 384 + ks * 32 + lk);
            acc = __builtin_amdgcn_mfma_f32_16x16x32_bf16(a, bb, acc, 0, 0, 0);
        }
        const int colf = nt2 * 16 + l15;
        const float b2 = fc2_b[colf];
        #pragma unroll
        for (int rr = 0; rr < 4; ++rr) {
            const size_t o = (r0 + mt2 * 16 + g4 + rr) * CDIM + colf;
            io[o] = io[o] + acc[rr] + b2;
        }
    }
}

extern "C" void kernel_launch(void* const* d_in, const int* in_sizes, int n_in,
                              void* d_out, int out_size, void* d_ws, size_t ws_size,
                              hipStream_t stream) {
    (void)n_in; (void)out_size; (void)ws_size;
    const float* x        = (const float*)d_in[0];
    const float* attn_msk = (const float*)d_in[1];
    const float* ln1_g    = (const float*)d_in[2];
    const float* ln1_b    = (const float*)d_in[3];
    const float* qkv_w    = (const float*)d_in[4];
    const float* qkv_b    = (const float*)d_in[5];
    const float* rel_tab  = (const float*)d_in[6];
    const int*   rel_idx  = (const int*)d_in[7];
    const float* proj_w   = (const float*)d_in[8];
    const float* proj_b   = (const float*)d_in[9];
    const float* ln2_g    = (const float*)d_in[10];
    const float* ln2_b    = (const float*)d_in[11];
    const float* fc1_w    = (const float*)d_in[12];
    const float* fc1_b    = (const float*)d_in[13];
    const float* fc2_w    = (const float*)d_in[14];
    const float* fc2_b    = (const float*)d_in[15];
    float* out = (float*)d_out;
    unsigned short* wsb = (unsigned short*)d_ws;
    unsigned short* bmf = wsb + 110592;

    const int B = in_sizes[0] / (3136 * 96);   // 64

    conv_w_kernel<<<(110592 + 255) / 256, 256, 0, stream>>>(qkv_w, proj_w, fc1_w, fc2_w, wsb);
    build_bmfrag_kernel<<<196608 / 256, 256, 0, stream>>>(attn_msk, rel_tab, rel_idx, bmf);

    swin_attn_mfma<<<B * 64, 512, 0, stream>>>(
        x, ln1_g, ln1_b, qkv_b, proj_b,
        wsb, wsb + 27648, bmf, out);

    swin_mlp_mfma<<<(B * 3136) / 128, 1024, 0, stream>>>(
        ln2_g, ln2_b, fc1_b, fc2_b, wsb + 36864, wsb + 73728, out);
}